// Round 6
// baseline (133.877 us; speedup 1.0000x reference)
//
#include <hip/hip_runtime.h>
#include <math.h>

// Problem: SphericalHarmonicTransform, L=8, RCUT=5, N=4194304 points.
// out[81] = sum over points of (modified) solid harmonic terms.
// R15: VGPR trim to cross the 3-waves/SIMD occupancy boundary.
//     New model (closed on R13 data): accumulators (81) live in AGPRs; the
//     unified V+A file (512 regs/SIMD) throttles residency. R13: V76(->80) +
//     A~96 = 176/wave -> 2 waves/SIMD = 25% occ (matches). R12: V152+A112 ->
//     1 wave/SIMD = 12.5% (matches). Need total <= ~170 for 3 waves/SIMD:
//     trim V76 -> ~60 by dropping two redundant tables, recomputed with
//     BITWISE-IDENTICAL op sequences:
//       (a) sqa[9]: aa[p]*aa[p] inline at each use (+11 muls, -9 regs)
//       (b) h[9]: running left-assoc products hbase/hl reproducing the exact
//           h[l]=h[l-1]*inv chain (+36 muls, -9 regs)
//     asm identity barriers ("+v") stop GVN re-CSE-ing the tables back.
//     Trade: +~94 VALU-cy/point (~11%) for +50% resident waves; each wave
//     issues only ~17% of cycles (packed deps, v_pk = 4cy no-rate-advantage),
//     so VALUBusy should scale with waves: 49% -> 62-72%.
//     Predicted: VGPR 56-66 (>=72 -> void), occ 25 -> 35-38%, sht_main 70 ->
//     50-57us. Guards: WRITE_SIZE 2.6MB (no spill), absmax 0.0.
//     If VGPR drops but occ stays 25%: granularity theory wrong -> pivot to
//     1-wave blocks (removes block-granularity allocation).
// Known-good: un-unrolled point loop (R13, -6%: I$ minor); (256,1).
// Known-bad: launch_bounds(256,4) -> V64 clamp + 1.1GB spill (R2);
//     waves_per_eu(2,2) -> 128 clamp + spill (R10); f32x4 2-pt interleave ->
//     +44 VGPR, 1 wave/SIMD, 119us (R12); pack/extract reshape (R8);
//     fused finalize (R5); per-point prefetch (R4).

typedef float f32x2 __attribute__((ext_vector_type(2)));

#define NL 8               // L
#define NBLK 1024
#define NTHR 256

__device__ __forceinline__ f32x2 sp(float v) { return f32x2{v, v}; }

__device__ __forceinline__ f32x2 pkfma(f32x2 a, f32x2 b, f32x2 c) {
    return __builtin_elementwise_fma(a, b, c);
}

// a*b with an opaque SSA def: blocks GVN/CSE from rebuilding a table of
// these products across the unrolled m-loop. Zero extra instructions,
// bitwise-identical value.
__device__ __forceinline__ float omul(float a, float b) {
    float r = a * b;
    asm("" : "+v"(r));
    return r;
}

__device__ __forceinline__ float waveReduce(float v) {
    v += __shfl_down(v, 32);
    v += __shfl_down(v, 16);
    v += __shfl_down(v, 8);
    v += __shfl_down(v, 4);
    v += __shfl_down(v, 2);
    v += __shfl_down(v, 1);
    return v;
}

// One point, fully unrolled. acc0 = m=0 reals (9); accp = m>=1 (re,im) pairs (36).
// Arithmetic bit-identical to R9/R13 (same ops, same operand order).
__device__ __forceinline__ void point_body(float x, float y, float z,
                                           float* __restrict__ acc0,
                                           f32x2* __restrict__ accp) {
    const float FACT[9] = {1.f, 1.f, 2.f, 6.f, 24.f, 120.f, 720.f, 5040.f, 40320.f};

    const float r2 = x * x + y * y + z * z;
    const bool valid = r2 > 0.0f;
    const float inv0 = __builtin_amdgcn_rsqf(r2);      // 1/sqrt(r2)
    const float norm = r2 * inv0;                      // sqrt(r2); NaN at 0, masked
    float cut = 0.5f * (__cosf(norm * 0.6283185307179586f) + 1.0f);
    cut = (r2 > 25.0f) ? 0.0f : cut;
    cut = valid ? cut : 0.0f;                          // kills NaN at r2=0
    const float inv = valid ? inv0 : 1.0f;             // safe 1/norm
    const float x0c = z * cut;

    // packed chains: lane0 = z1 (xp), lane1 = z2 (xm)
    const f32x2 w  = { -0.5f * x,  0.5f * x };         // (xpr, xmr)
    const f32x2 wi = { -0.5f * y, -0.5f * y };         // (xpi, xmi)

    // powcmplx replication:
    //  n=0 -> (1,0); n=1 -> w; n=2 -> special (r^2-i^2, 2ri);
    //  n>=3 -> buggy chain: nr = wr*br - wi*bi; ni = wr*bi + wi*nr (uses NEW nr)
    //  chain's k=2 real == special real; its (buggy) imag feeds k>=3.
    f32x2 zr[9], zi[9];
    zr[0] = sp(1.f); zi[0] = sp(0.f);
    zr[1] = w;       zi[1] = wi;
    zr[2] = w * w - wi * wi;
    zi[2] = (w + w) * wi;                              // 2*wr*wi
    {
        f32x2 cr = zr[2];
        f32x2 ci = w * wi + wi * cr;                   // buggy chain imag at k=2
#pragma unroll
        for (int k = 3; k <= NL; ++k) {
            const f32x2 nr = w * cr - wi * ci;
            const f32x2 ni = w * ci + wi * nr;         // buggy: uses nr
            cr = nr; ci = ni;
            zr[k] = nr; zi[k] = ni;
        }
    }

    // unpack views (register aliases, free). NO sqa table (R15): aa*aa is
    // recomputed at each use via omul (bitwise-identical product).
    float aa[9], bb[9], cc[9], dd[9];
#pragma unroll
    for (int p = 0; p <= NL; ++p) {
        aa[p] = zr[p].x;   // z1r
        cc[p] = zr[p].y;   // z2r
        bb[p] = zi[p].x;   // z1i
        dd[p] = zi[p].y;   // z2i
    }

    // NO h table (R15): running products reproduce h[l] = h[l-1]*inv exactly
    // (same left-assoc multiply chain -> bitwise-identical values).

    // ---- m = 0: pure-real scalar path (no dead imag work) ----
    {
        float Y0[5];                                    // p = q, p <= 4
#pragma unroll
        for (int p = 0; p <= 4; ++p) {
            const float cpq = 1.0f / (FACT[p] * FACT[p]);       // compile-time
            Y0[p] = fmaf(-dd[p], dd[p], omul(aa[p], aa[p])) * cpq;
        }
        float hl = x0c;                                 // == h[0]
#pragma unroll
        for (int l = 0; l <= NL; ++l) {
            float sr = 0.f;
#pragma unroll
            for (int p = 0; p <= 4; ++p) {
                if (2 * p <= l) {
                    const float is = 1.0f / FACT[l - 2 * p];    // 9 uniques
                    sr = fmaf(Y0[p], is, sr);
                }
            }
            acc0[l] = fmaf(sr, hl, acc0[l]);
            if (l < NL) {                               // skip dead tail mul
                hl = hl * inv;                          // == h[l+1], exact chain
                asm("" : "+v"(hl));
            }
        }
    }

    // ---- m >= 1: packed (real, imag) ----
    float hbase = x0c;                                  // will become h[m]
#pragma unroll
    for (int m = 1; m <= NL; ++m) {
        hbase = hbase * inv;                            // == h[m], exact chain
        asm("" : "+v"(hbase));
        f32x2 Y[9];
#pragma unroll
        for (int p = 0; p <= NL; ++p) {
            if (p >= m && 2 * p - m <= NL) {
                const int q = p - m;
                const float cpq = 1.0f / (FACT[p] * FACT[q]);   // compile-time
                const float bc = bb[p] * cc[q];
                const f32x2 A = { -dd[q], aa[p] };
                const f32x2 B = {  dd[q], dd[q] };
                const f32x2 C = { omul(aa[p], aa[p]), bc };
                Y[p] = pkfma(A, B, C) * sp(cpq);
            }
        }
        float hl = hbase;                               // == h[m]
#pragma unroll
        for (int l = m; l <= NL; ++l) {
            f32x2 s = sp(0.f);
#pragma unroll
            for (int p = 0; p <= NL; ++p) {
                if (p >= m && 2 * p - m <= l) {
                    const float is = 1.0f / FACT[l - 2 * p + m]; // 9 uniques
                    s = pkfma(Y[p], sp(is), s);
                }
            }
            // accp index: t(l,m) = l*(l-1)/2 + (m-1)
            const int ai = l * (l - 1) / 2 + (m - 1);
            accp[ai] = pkfma(s, sp(hl), accp[ai]);
            if (l < NL) {                               // skip dead tail mul
                hl = hl * inv;                          // == h[l+1], exact chain
                asm("" : "+v"(hl));
            }
        }
    }
}

__global__ __launch_bounds__(256, 1)
void sht_main(const float* __restrict__ pos, float* __restrict__ ws, int n) {
    float acc0[9];
    f32x2 accp[36];
#pragma unroll
    for (int i = 0; i < 9; ++i) acc0[i] = 0.f;
#pragma unroll
    for (int i = 0; i < 36; ++i) accp[i] = sp(0.f);

    const int t = blockIdx.x * NTHR + threadIdx.x;
    const int nthreads = NBLK * NTHR;                       // 262144
    const int nchunks = (n / 8 + nthreads - 1) / nthreads;  // 2 for N=2^22

    // Same ownership & order as R9/R13 (thread owns 8 contiguous points per
    // chunk, processed in order) -> bit-identical accumulation. Un-unrolled
    // point loop keeps the hot body I$-resident (R13, known-good).
    for (int c = 0; c < nchunks; ++c) {
        const int idx = (c * nthreads + t) * 8;             // 8 contiguous points
#pragma unroll 1
        for (int k = 0; k < 8; ++k) {
            const int i = idx + k;
            float x, y, z;
            if (i < n) {
                x = pos[3 * i + 0];                         // dwordx3; k and k+1
                y = pos[3 * i + 1];                         // share cache lines
                z = pos[3 * i + 2];
            } else {
                x = 0.f; y = 0.f; z = 0.f;                  // zero-pad: adds 0
            }
            point_body(x, y, z, acc0, accp);
        }
    }

    // ---- reduction: wave shuffle -> LDS across 4 waves -> per-block row ----
    __shared__ float red[81][5];   // [out slot][wave], padded stride
    const int lane = threadIdx.x & 63;
    const int wave = threadIdx.x >> 6;

#pragma unroll
    for (int l = 0; l <= NL; ++l) {
        float vr = waveReduce(acc0[l]);
        if (lane == 0) red[l * l + l][wave] = vr;
    }
#pragma unroll
    for (int m = 1; m <= NL; ++m) {
#pragma unroll
        for (int l = m; l <= NL; ++l) {
            const int ai = l * (l - 1) / 2 + (m - 1);
            float vr = waveReduce(accp[ai].x);
            if (lane == 0) red[l * l + l + m][wave] = vr;
            float vi = waveReduce(accp[ai].y);
            if (lane == 0) red[l * l + l - m][wave] = vi;
        }
    }
    __syncthreads();

    // transposed partials: ws[slot*NBLK + block] -> coalesced finalize reads
    if ((int)threadIdx.x < 81) {
        float s = 0.f;
#pragma unroll
        for (int w = 0; w < 4; ++w) s += red[threadIdx.x][w];
        ws[(size_t)threadIdx.x * NBLK + blockIdx.x] = s;
    }
}

__device__ double dfact(int nn) {
    double r = 1.0;
    for (int i = 2; i <= nn; ++i) r *= (double)i;
    return r;
}

// one block per output slot; 256 threads sum 1024 coalesced partials
__global__ __launch_bounds__(256)
void sht_finalize(const float* __restrict__ ws, float* __restrict__ out) {
    const int j = blockIdx.x;       // 0..80
    const int t = threadIdx.x;
    float s = 0.f;
#pragma unroll
    for (int k = 0; k < NBLK / 256; ++k)
        s += ws[(size_t)j * NBLK + k * 256 + t];
    s = waveReduce(s);

    __shared__ float red[4];
    const int lane = t & 63, wave = t >> 6;
    if (lane == 0) red[wave] = s;
    __syncthreads();
    if (t == 0) {
        float tot = red[0] + red[1] + red[2] + red[3];
        int l = 0;
        while ((l + 1) * (l + 1) <= j) ++l;
        const int M = j - l * l - l;
        const int m = (M < 0) ? -M : M;
        // f = sqrt((l+m)!(l-m)!); k_l = sqrt((2l+1)/(4*3.14159))  (ref PI=3.14159)
        double sc = sqrt(dfact(l + m) * dfact(l - m)) *
                    sqrt((double)(2 * l + 1) / (4.0 * 3.14159));
        if (m > 0) sc *= sqrt(2.0) * ((m & 1) ? -1.0 : 1.0);
        out[j] = (float)((double)tot * sc);
    }
}

extern "C" void kernel_launch(void* const* d_in, const int* in_sizes, int n_in,
                              void* d_out, int out_size, void* d_ws, size_t ws_size,
                              hipStream_t stream) {
    const float* pos = (const float*)d_in[0];
    const int npts = in_sizes[0] / 3;
    float* ws = (float*)d_ws;
    float* out = (float*)d_out;

    sht_main<<<NBLK, NTHR, 0, stream>>>(pos, ws, npts);
    sht_finalize<<<81, 256, 0, stream>>>(ws, out);
}